// Round 4
// baseline (2802.187 us; speedup 1.0000x reference)
//
#include <hip/hip_runtime.h>
#include <hip/hip_bf16.h>

// LSTM: N=640 seqs (B*Q fused), T=100, D=H=512. Inputs fp32; d_out fp32.
// R10 on R9 (passing, 1968us dispatch = 19.7us/step, all pipes <8% busy):
//   R9 post-mortem: per-step chain latency, not work. Three chain cuts:
//   1) UNIFORM GRID: 8 groups x 80 seqs = 256 blocks, 1/CU (was 320 on
//      256 -> 64 CUs doubled -> per-group straggler every step). M-tile 80
//      (5 MFMA row-tiles), LDS 62.7KB <= 80KB -> 2-block/CU capacity ->
//      all 256 resident under ANY placement (deadlock-safe, no coop).
//   2) PER-PRODUCER FLAGS (no RMW): producer stores t+1 to its own slot
//      after h-drain barrier (32-way LLC atomic-add serialization + one
//      round trip gone). Consumer: wave0 lanes 0-31 poll the 32 flags,
//      __all(v>=t) detect, no s_sleep.
//   3) h BROADCAST VIA CONSUMER L2: 100 rotating h buffers (65.5MB ws) ->
//      consumer plain loads are guaranteed-cold L2 misses (fresh addr per
//      step; dispatch-start acquire invalidates prior launches) -> 4
//      same-XCD consumers share one L2 fetch (32x -> 8x amplification).
//      Stores remain LLC-bypass write-through (cross-XCD freshness).
//      Fallback (small ws): R9's bypass-load ping-pong.
//   + fast tanh via __expf (shortens serial epilogue).
//   Kept: weights in 128 VGPRs loaded once, c in regs, biases preloaded,
//   x-GEMM before the wait (overlaps sibling skew), t=0 skips h-phase,
//   2-half K staging w/ XOR swizzle (proven), pair-packed h stores.

#define T_ 100
#define D_ 512
#define H_ 512
#define N_ 640
#define NSB 8    // seq-groups
#define MS  80   // seqs per group (5 x 16-row MFMA tiles)
#define NGR 32   // hcol groups (16 cols x 4 gates each)

using short8  = __attribute__((ext_vector_type(8))) short;  // 8 bf16
using floatx4 = __attribute__((ext_vector_type(4))) float;  // MFMA C/D

__device__ __forceinline__ float sigmoidf_(float x) {
    return 1.0f / (1.0f + __expf(-x));
}

__device__ __forceinline__ float tanhf_(float x) {  // fast, |err|~1e-7
    const float e = __expf(2.0f * x);
    return 1.0f - 2.0f / (e + 1.0f);   // +inf->1, 0->-1 handled
}

__device__ __forceinline__ unsigned short f2bf(float f) {  // RNE, finite inputs
    union { float f; unsigned int u; } v; v.f = f;
    unsigned int u = v.u;
    u += 0x7fffu + ((u >> 16) & 1u);
    return (unsigned short)(u >> 16);
}

__device__ __forceinline__ short8 cvt8(const float* __restrict__ p) {
    const float4 a = *(const float4*)p;
    const float4 b = *(const float4*)(p + 4);
    short8 r;
    r[0] = (short)f2bf(a.x); r[1] = (short)f2bf(a.y);
    r[2] = (short)f2bf(a.z); r[3] = (short)f2bf(a.w);
    r[4] = (short)f2bf(b.x); r[5] = (short)f2bf(b.y);
    r[6] = (short)f2bf(b.z); r[7] = (short)f2bf(b.w);
    return r;
}

// fp32 -> bf16, 8 elements/thread
__global__ __launch_bounds__(256) void cvt_bf16(const float* __restrict__ src,
                                                unsigned short* __restrict__ dst, int n) {
    const int i = (blockIdx.x * 256 + threadIdx.x) * 8;
    if (i < n) {
        const float4 a = *(const float4*)(src + i);
        const float4 b = *(const float4*)(src + i + 4);
        ushort4 o0, o1;
        o0.x = f2bf(a.x); o0.y = f2bf(a.y); o0.z = f2bf(a.z); o0.w = f2bf(a.w);
        o1.x = f2bf(b.x); o1.y = f2bf(b.y); o1.z = f2bf(b.z); o1.w = f2bf(b.w);
        *(ushort4*)(dst + i)     = o0;
        *(ushort4*)(dst + i + 4) = o1;
    }
}

template <bool XBF, bool MULTI>
__global__ __launch_bounds__(256, 2) void lstm_persist(
    const void* __restrict__ xsrc,             // [N,T,D] bf16 (XBF) else fp32
    const __hip_bfloat16* __restrict__ Wih,    // [4H, D] bf16
    const __hip_bfloat16* __restrict__ Whh,    // [4H, H] bf16
    const float* __restrict__ bih,             // [4H]
    const float* __restrict__ bhh,             // [4H]
    __hip_bfloat16* __restrict__ hbuf,         // MULTI: [T][N,H]; else ping/pong x2
    float* __restrict__ out,                   // d_out fp32 [N,H]
    int* __restrict__ flags)                   // [NSB][NGR] step flags (zeroed)
{
    __shared__ unsigned char A[MS * 512];  // 80 rows x 256 bf16 (half-K), swizzled
    __shared__ float G[4][MS][17];         // gate exchange; total 62720 B

    const int tid = threadIdx.x;
    const int bid = blockIdx.x;
    const int sb   = bid >> 5;   // 0..7 ; group's 32 blocks have bid&7 = all XCDs x4
    const int grp  = bid & 31;
    const int gate = tid >> 6;
    const int lane = tid & 63;
    const int l15  = lane & 15;
    const int quad = lane >> 4;
    const int seq0 = sb * MS;
    const int hc0  = grp * 16;

    const int r = gate * H_ + hc0 + l15;  // W row (output gate-col) for this lane

    // ---- weight slice in registers, loaded ONCE ----
    short8 wreg[2][4][4];  // [phase][k-128chunk][ki]
    {
        const __hip_bfloat16* w0 = Wih + (size_t)r * 512 + quad * 8;
        const __hip_bfloat16* w1 = Whh + (size_t)r * 512 + quad * 8;
        #pragma unroll
        for (int c = 0; c < 4; ++c)
            #pragma unroll
            for (int k = 0; k < 4; ++k) {
                wreg[0][c][k] = *(const short8*)(w0 + c * 128 + k * 32);
                wreg[1][c][k] = *(const short8*)(w1 + c * 128 + k * 32);
            }
    }

    // ---- fixed epilogue column: preload bias sums ----
    const int colj = hc0 + (tid & 15);
    const float bi = bih[0 * H_ + colj] + bhh[0 * H_ + colj];
    const float bf = bih[1 * H_ + colj] + bhh[1 * H_ + colj];
    const float bg = bih[2 * H_ + colj] + bhh[2 * H_ + colj];
    const float bo = bih[3 * H_ + colj] + bhh[3 * H_ + colj];

    float creg[5] = {0.f, 0.f, 0.f, 0.f, 0.f};  // c state, block-exclusive

    const float*          af0 = XBF ? nullptr : (const float*)xsrc + (size_t)seq0 * T_ * D_;
    const __hip_bfloat16* ab0 = XBF ? (const __hip_bfloat16*)xsrc + (size_t)seq0 * T_ * D_ : nullptr;
    const size_t nH = (size_t)N_ * H_;

    #pragma unroll 1
    for (int t = 0; t < T_; ++t) {
        const __hip_bfloat16* hp = MULTI ? hbuf + (size_t)(t - 1) * nH      // valid t>0
                                         : hbuf + ((t & 1) ? nH : 0);
        __hip_bfloat16*       hn = MULTI ? hbuf + (size_t)t * nH
                                         : hbuf + ((t & 1) ? 0 : nH);

        floatx4 acc[5] = {};

        // ================= phase 0: x_t @ Wih^T (no h needed) =================
        {
            const size_t astr = (size_t)T_ * D_;
            const size_t toff = (size_t)t * D_;
            #pragma unroll
            for (int half = 0; half < 2; ++half) {
                const int kc = half * 256;
                __syncthreads();  // previous A readers done
                #pragma unroll
                for (int u = 0; u < 10; ++u) {      // 2560 x 16B slots
                    const int slot = u * 256 + tid;
                    const int row  = slot >> 5;
                    const int c16  = slot & 31;
                    short8 v;
                    if (XBF) v = *(const short8*)(ab0 + row * astr + toff + kc + c16 * 8);
                    else     v = cvt8(af0 + row * astr + toff + kc + c16 * 8);
                    *(short8*)(A + row * 512 + ((c16 << 4) ^ ((row & 7) << 4))) = v;
                }
                __syncthreads();
                #pragma unroll
                for (int kk = 0; kk < 8; ++kk) {   // 8 x K=32
                    const short8 bfrag = wreg[0][half * 2 + (kk >> 2)][kk & 3];
                    #pragma unroll
                    for (int mi = 0; mi < 5; ++mi) {
                        const int row = mi * 16 + l15;
                        const short8 afrag = *(const short8*)(
                            A + row * 512 + (((kk << 6) + (quad << 4)) ^ ((row & 7) << 4)));
                        acc[mi] = __builtin_amdgcn_mfma_f32_16x16x32_bf16(afrag, bfrag,
                                                                          acc[mi], 0, 0, 0);
                    }
                }
            }
        }

        // ================= phase 1: h_{t-1} @ Whh^T =================
        if (t > 0) {
            // wait: 32 lanes of wave 0 each poll one producer flag
            if (tid < 64) {
                const int* fp = flags + sb * 32 + (tid & 31);
                int v = 0x7fffffff;
                for (;;) {
                    if (tid < 32)
                        v = __hip_atomic_load(fp, __ATOMIC_RELAXED, __HIP_MEMORY_SCOPE_AGENT);
                    if (__all(v >= t)) break;
                }
            }
            __syncthreads();  // h ready; also x-GEMM A readers done

            const unsigned long long* hp8 =
                (const unsigned long long*)(hp + (size_t)seq0 * H_);
            #pragma unroll
            for (int half = 0; half < 2; ++half) {
                const int kc8 = half * 64;        // 8B units within row (256 bf16)
                if (half) __syncthreads();        // previous-half A readers done
                #pragma unroll
                for (int u = 0; u < 20; ++u) {    // 5120 x 8B slots
                    const int slot = u * 256 + tid;
                    const int row  = slot >> 6;
                    const int c8   = slot & 63;
                    unsigned long long v;
                    if (MULTI)   // plain load: fresh buffer -> guaranteed-cold, L2-shared
                        v = *(hp8 + row * 128 + kc8 + c8);
                    else         // ping-pong: must bypass L2 (staleness)
                        v = __hip_atomic_load(hp8 + row * 128 + kc8 + c8,
                                              __ATOMIC_RELAXED, __HIP_MEMORY_SCOPE_AGENT);
                    *(unsigned long long*)(A + row * 512 +
                                           ((c8 << 3) ^ ((row & 7) << 4))) = v;
                }
                __syncthreads();
                #pragma unroll
                for (int kk = 0; kk < 8; ++kk) {
                    const short8 bfrag = wreg[1][half * 2 + (kk >> 2)][kk & 3];
                    #pragma unroll
                    for (int mi = 0; mi < 5; ++mi) {
                        const int row = mi * 16 + l15;
                        const short8 afrag = *(const short8*)(
                            A + row * 512 + (((kk << 6) + (quad << 4)) ^ ((row & 7) << 4)));
                        acc[mi] = __builtin_amdgcn_mfma_f32_16x16x32_bf16(afrag, bfrag,
                                                                          acc[mi], 0, 0, 0);
                    }
                }
            }
        }

        // ================= epilogue =================
        // C/D: col = lane&15 (hcol), row = quad*4 + reg (seq)
        #pragma unroll
        for (int mi = 0; mi < 5; ++mi)
            #pragma unroll
            for (int rg = 0; rg < 4; ++rg)
                G[gate][mi * 16 + quad * 4 + rg][l15] = acc[mi][rg];
        __syncthreads();

        #pragma unroll
        for (int i = 0; i < 5; ++i) {
            const int sl = (tid >> 4) + 16 * i;   // 0..79
            const int cc = tid & 15;
            const int n  = seq0 + sl;

            const float gi = sigmoidf_(G[0][sl][cc] + bi);
            const float gf = sigmoidf_(G[1][sl][cc] + bf);
            const float gg = tanhf_(G[2][sl][cc] + bg);
            const float go = sigmoidf_(G[3][sl][cc] + bo);

            const float cn = gf * creg[i] + gi * gg;
            creg[i] = cn;
            const float hv = go * tanhf_(cn);

            if (t < T_ - 1) {
                // lanes (tid,tid^1) hold cols (cc,cc^1): pack -> one 32-bit
                // LLC write-through store (no fence needed)
                const unsigned int hb    = f2bf(hv);
                const unsigned int other = __shfl_xor((int)hb, 1, 64);
                if ((tid & 1) == 0) {
                    unsigned int packed = hb | (other << 16);
                    __hip_atomic_store(
                        (unsigned int*)((unsigned short*)hn + (size_t)n * H_ + colj),
                        packed, __ATOMIC_RELAXED, __HIP_MEMORY_SCOPE_AGENT);
                }
            } else {
                out[(size_t)n * H_ + colj] = hv;  // kernel-end release covers d_out
            }
        }

        // ---- publish h(t): drain stores, block-barrier, own-flag store ----
        if (t < T_ - 1) {
            asm volatile("s_waitcnt vmcnt(0)" ::: "memory");  // h stores at LLC
            __syncthreads();                                  // whole block drained
            if (tid == 0)
                __hip_atomic_store(flags + sb * 32 + grp, t + 1,
                                   __ATOMIC_RELAXED, __HIP_MEMORY_SCOPE_AGENT);
        }
    }
}

extern "C" void kernel_launch(void* const* d_in, const int* in_sizes, int n_in,
                              void* d_out, int out_size, void* d_ws, size_t ws_size,
                              hipStream_t stream) {
    const float* x    = (const float*)d_in[0];
    const float* Wihf = (const float*)d_in[1];
    const float* Whhf = (const float*)d_in[2];
    const float* bih  = (const float*)d_in[3];
    const float* bhh  = (const float*)d_in[4];

    const size_t nW = (size_t)4 * H_ * D_;   // 1,048,576
    const size_t nX = (size_t)N_ * T_ * D_;  // 32,768,000
    const size_t nH = (size_t)N_ * H_;       // 327,680

    // ws: Wb | Ub | flags | h0 | h1 | [xb] | [hmulti (T_ buffers)]
    char* p = (char*)d_ws;
    __hip_bfloat16* Wb = (__hip_bfloat16*)p;  p += nW * 2;
    __hip_bfloat16* Ub = (__hip_bfloat16*)p;  p += nW * 2;
    int* flags = (int*)p;                     p += 4096;   // 1024 B used
    __hip_bfloat16* h2 = (__hip_bfloat16*)p;  p += nH * 2 * 2;  // ping+pong
    const size_t need_xb = (size_t)(p - (char*)d_ws) + nX * 2;
    const bool use_xb = ws_size >= need_xb;
    __hip_bfloat16* xb = use_xb ? (__hip_bfloat16*)p : nullptr;
    if (use_xb) p += nX * 2;
    const size_t need_hm = (size_t)(p - (char*)d_ws) + (size_t)T_ * nH * 2;
    const bool use_hm = use_xb && (ws_size >= need_hm);
    __hip_bfloat16* hm = use_hm ? (__hip_bfloat16*)p : h2;

    cvt_bf16<<<(int)(nW / (256 * 8)), 256, 0, stream>>>(Wihf, (unsigned short*)Wb, (int)nW);
    cvt_bf16<<<(int)(nW / (256 * 8)), 256, 0, stream>>>(Whhf, (unsigned short*)Ub, (int)nW);
    if (use_xb)
        cvt_bf16<<<(int)(nX / (256 * 8)), 256, 0, stream>>>(x, (unsigned short*)xb, (int)nX);

    hipMemsetAsync(flags, 0, 4096, stream);

    const int nblk = NSB * NGR;  // 256 blocks, 1/CU; capacity 2/CU -> all resident
    if (use_hm)
        lstm_persist<true, true><<<nblk, 256, 0, stream>>>(xb, Wb, Ub, bih, bhh, hm,
                                                           (float*)d_out, flags);
    else if (use_xb)
        lstm_persist<true, false><<<nblk, 256, 0, stream>>>(xb, Wb, Ub, bih, bhh, hm,
                                                            (float*)d_out, flags);
    else
        lstm_persist<false, false><<<nblk, 256, 0, stream>>>(x, Wb, Ub, bih, bhh, hm,
                                                             (float*)d_out, flags);
}

// Round 5
// 2423.697 us; speedup vs baseline: 1.1562x; 1.1562x over previous
//
#include <hip/hip_runtime.h>
#include <hip/hip_bf16.h>

// LSTM: N=640 seqs (B*Q fused), T=100, D=H=512. Inputs fp32; d_out fp32.
// R11 = R10's uniform grid + R9's proven memory protocol + XCD locality.
//   R10 post-mortem (2721us, FETCH 710MB, WRITE 1.09GB): MULTI rotating h
//   buffers streamed 65MB through LLC w/ 4B->32B write amplification, and
//   dropping the XCD mapping spread each group's x-tile over 8 L2s; h
//   streams thrashed x out of LLC -> ~6MB/step x re-fetch from HBM on the
//   critical path. Both reverted.
//   - GROUP = XCD: sb=bid&7, grp=bid>>3 -> a seq-group's 32 blocks share
//     one XCD (empirical bid%8 round-robin; perf-only, correctness never
//     depends on placement). Per-step 80KB x-tile -> one L2, 32 sharers.
//   - h exchange = R9 protocol (measured FETCH 127MB/WRITE 82MB): ping-pong
//     2 buffers; relaxed AGENT atomic stores (write-through LLC, sc0 sc1)
//     + relaxed AGENT atomic loads (LLC, never stale); publish = vmcnt(0)
//     drain + block barrier + own-flag store; NO fences (no buffer_inv/wbl2).
//   - 6 barriers/step (was ~10): full 80-row x 512-col tile staged in one
//     shot into two 40KB half-K buffers; G[4][80][17] OVERLAYS the same
//     80KB LDS region (epilogue only; existing barriers order the reuse).
//     80KB LDS -> 2-block/CU capacity -> all 256 blocks co-resident under
//     ANY placement (deadlock-safe, no cooperative launch).
//   - __launch_bounds__(256,1): R9/R10 VGPR_Count=128 == weight bytes alone
//     -> compiler was re-loading weights per step. Full 512-VGPR budget
//     makes the 128-VGPR weight slice genuinely register-resident (needed:
//     per-XCD weight set is 8MB > 4MB L2 under the new mapping).
//   Kept: per-producer flags (no RMW serialization), wave0 32-lane poll,
//   x-GEMM before the wait, t=0 skips h-phase, fast tanh, pair-packed h
//   stores, XOR-swizzled LDS rows, c in regs, biases preloaded.

#define T_ 100
#define D_ 512
#define H_ 512
#define N_ 640
#define NSB 8      // seq-groups (one per XCD)
#define MS  80     // seqs per group (5 x 16-row MFMA tiles)
#define NGR 32     // hcol groups (16 cols x 4 gates each)
#define HALFB 40960  // bytes per half-K LDS buffer (80 rows x 512 B)

using short8  = __attribute__((ext_vector_type(8))) short;  // 8 bf16
using floatx4 = __attribute__((ext_vector_type(4))) float;  // MFMA C/D

__device__ __forceinline__ float sigmoidf_(float x) {
    return 1.0f / (1.0f + __expf(-x));
}

__device__ __forceinline__ float tanhf_(float x) {  // fast, |err|~1e-7
    const float e = __expf(2.0f * x);
    return 1.0f - 2.0f / (e + 1.0f);
}

__device__ __forceinline__ unsigned short f2bf(float f) {  // RNE, finite inputs
    union { float f; unsigned int u; } v; v.f = f;
    unsigned int u = v.u;
    u += 0x7fffu + ((u >> 16) & 1u);
    return (unsigned short)(u >> 16);
}

__device__ __forceinline__ short8 cvt8(const float* __restrict__ p) {
    const float4 a = *(const float4*)p;
    const float4 b = *(const float4*)(p + 4);
    short8 r;
    r[0] = (short)f2bf(a.x); r[1] = (short)f2bf(a.y);
    r[2] = (short)f2bf(a.z); r[3] = (short)f2bf(a.w);
    r[4] = (short)f2bf(b.x); r[5] = (short)f2bf(b.y);
    r[6] = (short)f2bf(b.z); r[7] = (short)f2bf(b.w);
    return r;
}

// fp32 -> bf16, 8 elements/thread
__global__ __launch_bounds__(256) void cvt_bf16(const float* __restrict__ src,
                                                unsigned short* __restrict__ dst, int n) {
    const int i = (blockIdx.x * 256 + threadIdx.x) * 8;
    if (i < n) {
        const float4 a = *(const float4*)(src + i);
        const float4 b = *(const float4*)(src + i + 4);
        ushort4 o0, o1;
        o0.x = f2bf(a.x); o0.y = f2bf(a.y); o0.z = f2bf(a.z); o0.w = f2bf(a.w);
        o1.x = f2bf(b.x); o1.y = f2bf(b.y); o1.z = f2bf(b.z); o1.w = f2bf(b.w);
        *(ushort4*)(dst + i)     = o0;
        *(ushort4*)(dst + i + 4) = o1;
    }
}

template <bool XBF>
__global__ __launch_bounds__(256, 1) void lstm_persist(
    const void* __restrict__ xsrc,             // [N,T,D] bf16 (XBF) else fp32
    const __hip_bfloat16* __restrict__ Wih,    // [4H, D] bf16
    const __hip_bfloat16* __restrict__ Whh,    // [4H, H] bf16
    const float* __restrict__ bih,             // [4H]
    const float* __restrict__ bhh,             // [4H]
    __hip_bfloat16* __restrict__ hbuf,         // ping/pong [2][N,H] bf16
    float* __restrict__ out,                   // d_out fp32 [N,H]
    int* __restrict__ flags)                   // [NSB][NGR] step flags (zeroed)
{
    __shared__ unsigned char SMEM[2 * HALFB];  // 80 KiB: A(2 half-K bufs) ∪ G

    const int tid = threadIdx.x;
    const int bid = blockIdx.x;
    const int sb   = bid & 7;    // group = XCD (empirical bid%8; perf-only)
    const int grp  = bid >> 3;   // 0..31
    const int gate = tid >> 6;
    const int lane = tid & 63;
    const int l15  = lane & 15;
    const int quad = lane >> 4;
    const int seq0 = sb * MS;
    const int hc0  = grp * 16;

    const int r = gate * H_ + hc0 + l15;  // W row (output gate-col) for this lane

    // ---- weight slice in registers, loaded ONCE ----
    short8 wreg[2][4][4];  // [phase][k-128chunk][ki]; cols chunk*128+ki*32+quad*8
    {
        const __hip_bfloat16* w0 = Wih + (size_t)r * 512 + quad * 8;
        const __hip_bfloat16* w1 = Whh + (size_t)r * 512 + quad * 8;
        #pragma unroll
        for (int c = 0; c < 4; ++c)
            #pragma unroll
            for (int k = 0; k < 4; ++k) {
                wreg[0][c][k] = *(const short8*)(w0 + c * 128 + k * 32);
                wreg[1][c][k] = *(const short8*)(w1 + c * 128 + k * 32);
            }
    }

    // ---- fixed epilogue column: preload bias sums ----
    const int colj = hc0 + (tid & 15);
    const float bi = bih[0 * H_ + colj] + bhh[0 * H_ + colj];
    const float bf = bih[1 * H_ + colj] + bhh[1 * H_ + colj];
    const float bg = bih[2 * H_ + colj] + bhh[2 * H_ + colj];
    const float bo = bih[3 * H_ + colj] + bhh[3 * H_ + colj];

    float creg[5] = {0.f, 0.f, 0.f, 0.f, 0.f};  // c state, block-exclusive

    const float*          af0 = XBF ? nullptr : (const float*)xsrc + (size_t)seq0 * T_ * D_;
    const __hip_bfloat16* ab0 = XBF ? (const __hip_bfloat16*)xsrc + (size_t)seq0 * T_ * D_ : nullptr;
    const size_t nH = (size_t)N_ * H_;
    float* G = (float*)SMEM;  // [4][80][17] overlay, epilogue only

    #pragma unroll 1
    for (int t = 0; t < T_; ++t) {
        const __hip_bfloat16* hp = hbuf + ((t & 1) ? nH : 0);
        __hip_bfloat16*       hn = hbuf + ((t & 1) ? 0 : nH);

        floatx4 acc[5] = {};

        // ---- stage full x_t tile: 80 rows x 512 cols, both halves ----
        {
            const size_t astr = (size_t)T_ * D_;
            const size_t toff = (size_t)t * D_;
            #pragma unroll
            for (int u = 0; u < 20; ++u) {
                const int slot = u * 256 + tid;   // 5120 x 16B slots
                const int row  = slot >> 6;
                const int c32  = slot & 63;       // 16B unit within row
                const int half = c32 >> 5;
                const int c16  = c32 & 31;
                short8 v;
                if (XBF) v = *(const short8*)(ab0 + row * astr + toff + c32 * 8);
                else     v = cvt8(af0 + row * astr + toff + c32 * 8);
                *(short8*)(SMEM + half * HALFB + row * 512 +
                           ((c16 * 16) ^ ((row & 7) * 16))) = v;
            }
        }
        __syncthreads();  // (1) stage done
        // ---- x GEMM: K=512, 80 MFMA (before the wait: overlaps skew) ----
        #pragma unroll
        for (int kk = 0; kk < 16; ++kk) {
            const short8 bfrag = wreg[0][kk >> 2][kk & 3];
            const int half = kk >> 3, kk8 = kk & 7;
            #pragma unroll
            for (int mi = 0; mi < 5; ++mi) {
                const int row = mi * 16 + l15;
                const short8 afrag = *(const short8*)(
                    SMEM + half * HALFB + row * 512 +
                    (((kk8 * 64) + (quad * 16)) ^ ((row & 7) * 16)));
                acc[mi] = __builtin_amdgcn_mfma_f32_16x16x32_bf16(afrag, bfrag,
                                                                  acc[mi], 0, 0, 0);
            }
        }

        if (t > 0) {
            // ---- wait: wave0 lanes 0-31 poll this group's 32 flags ----
            if (tid < 64) {
                const int* fp = flags + sb * 32 + (tid & 31);
                int v = 0x7fffffff;
                for (;;) {
                    if (tid < 32)
                        v = __hip_atomic_load(fp, __ATOMIC_RELAXED,
                                              __HIP_MEMORY_SCOPE_AGENT);
                    if (__all(v >= t)) break;
                }
            }
            __syncthreads();  // (2) h ready; all x-GEMM A-reads done

            // ---- stage full h tile via LLC atomic loads ----
            const unsigned long long* hp8 =
                (const unsigned long long*)(hp + (size_t)seq0 * H_);
            #pragma unroll
            for (int u = 0; u < 40; ++u) {
                const int slot = u * 256 + tid;   // 10240 x 8B slots
                const int row  = slot >> 7;
                const int c64  = slot & 127;      // 8B unit within row
                const int half = c64 >> 6;
                const int c8   = c64 & 63;
                const unsigned long long v = __hip_atomic_load(
                    hp8 + row * 128 + c64, __ATOMIC_RELAXED,
                    __HIP_MEMORY_SCOPE_AGENT);
                *(unsigned long long*)(SMEM + half * HALFB + row * 512 +
                                       ((c8 * 8) ^ ((row & 7) * 16))) = v;
            }
            __syncthreads();  // (3) h staged
            // ---- h GEMM: K=512, 80 MFMA ----
            #pragma unroll
            for (int kk = 0; kk < 16; ++kk) {
                const short8 bfrag = wreg[1][kk >> 2][kk & 3];
                const int half = kk >> 3, kk8 = kk & 7;
                #pragma unroll
                for (int mi = 0; mi < 5; ++mi) {
                    const int row = mi * 16 + l15;
                    const short8 afrag = *(const short8*)(
                        SMEM + half * HALFB + row * 512 +
                        (((kk8 * 64) + (quad * 16)) ^ ((row & 7) * 16)));
                    acc[mi] = __builtin_amdgcn_mfma_f32_16x16x32_bf16(afrag, bfrag,
                                                                      acc[mi], 0, 0, 0);
                }
            }
        }

        // ---- epilogue: G overlays A (all A-reads done after barrier) ----
        __syncthreads();  // (4) A-reads complete before G overwrites
        // C/D: col = lane&15 (hcol), row = quad*4 + reg (seq)
        #pragma unroll
        for (int mi = 0; mi < 5; ++mi)
            #pragma unroll
            for (int rg = 0; rg < 4; ++rg)
                G[(gate * MS + mi * 16 + quad * 4 + rg) * 17 + l15] = acc[mi][rg];
        __syncthreads();  // (5) G visible

        #pragma unroll
        for (int i = 0; i < 5; ++i) {
            const int sl = (tid >> 4) + 16 * i;   // 0..79
            const int cc = tid & 15;
            const int n  = seq0 + sl;

            const float gi = sigmoidf_(G[(0 * MS + sl) * 17 + cc] + bi);
            const float gf = sigmoidf_(G[(1 * MS + sl) * 17 + cc] + bf);
            const float gg = tanhf_(G[(2 * MS + sl) * 17 + cc] + bg);
            const float go = sigmoidf_(G[(3 * MS + sl) * 17 + cc] + bo);

            const float cn = gf * creg[i] + gi * gg;
            creg[i] = cn;
            const float hv = go * tanhf_(cn);

            if (t < T_ - 1) {
                // lanes (tid,tid^1) hold cols (cc,cc^1): pack -> one 32-bit
                // LLC write-through store (no fence needed)
                const unsigned int hb    = f2bf(hv);
                const unsigned int other = __shfl_xor((int)hb, 1, 64);
                if ((tid & 1) == 0) {
                    unsigned int packed = hb | (other << 16);
                    __hip_atomic_store(
                        (unsigned int*)((unsigned short*)hn + (size_t)n * H_ + colj),
                        packed, __ATOMIC_RELAXED, __HIP_MEMORY_SCOPE_AGENT);
                }
            } else {
                out[(size_t)n * H_ + colj] = hv;  // kernel-end release covers d_out
            }
        }

        // ---- publish h(t): drain stores, block barrier, own-flag store ----
        if (t < T_ - 1) {
            asm volatile("s_waitcnt vmcnt(0)" ::: "memory");  // h stores at LLC
            __syncthreads();  // (6) whole block drained; also guards SMEM reuse
            if (tid == 0)
                __hip_atomic_store(flags + sb * 32 + grp, t + 1,
                                   __ATOMIC_RELAXED, __HIP_MEMORY_SCOPE_AGENT);
        }
    }
}

extern "C" void kernel_launch(void* const* d_in, const int* in_sizes, int n_in,
                              void* d_out, int out_size, void* d_ws, size_t ws_size,
                              hipStream_t stream) {
    const float* x    = (const float*)d_in[0];
    const float* Wihf = (const float*)d_in[1];
    const float* Whhf = (const float*)d_in[2];
    const float* bih  = (const float*)d_in[3];
    const float* bhh  = (const float*)d_in[4];

    const size_t nW = (size_t)4 * H_ * D_;   // 1,048,576
    const size_t nX = (size_t)N_ * T_ * D_;  // 32,768,000
    const size_t nH = (size_t)N_ * H_;       // 327,680

    // ws: Wb | Ub | flags | h ping+pong | [xb]
    char* p = (char*)d_ws;
    __hip_bfloat16* Wb = (__hip_bfloat16*)p;  p += nW * 2;
    __hip_bfloat16* Ub = (__hip_bfloat16*)p;  p += nW * 2;
    int* flags = (int*)p;                     p += 4096;   // 1024 B used
    __hip_bfloat16* h2 = (__hip_bfloat16*)p;  p += nH * 2 * 2;
    const size_t need_xb = (size_t)(p - (char*)d_ws) + nX * 2;
    const bool use_xb = ws_size >= need_xb;
    __hip_bfloat16* xb = use_xb ? (__hip_bfloat16*)p : nullptr;

    cvt_bf16<<<(int)(nW / (256 * 8)), 256, 0, stream>>>(Wihf, (unsigned short*)Wb, (int)nW);
    cvt_bf16<<<(int)(nW / (256 * 8)), 256, 0, stream>>>(Whhf, (unsigned short*)Ub, (int)nW);
    if (use_xb)
        cvt_bf16<<<(int)(nX / (256 * 8)), 256, 0, stream>>>(x, (unsigned short*)xb, (int)nX);

    hipMemsetAsync(flags, 0, 4096, stream);

    const int nblk = NSB * NGR;  // 256 blocks; 80KB LDS -> 2/CU capacity -> all resident
    if (use_xb)
        lstm_persist<true><<<nblk, 256, 0, stream>>>(xb, Wb, Ub, bih, bhh, h2,
                                                     (float*)d_out, flags);
    else
        lstm_persist<false><<<nblk, 256, 0, stream>>>(x, Wb, Ub, bih, bhh, h2,
                                                      (float*)d_out, flags);
}

// Round 6
// 1439.745 us; speedup vs baseline: 1.9463x; 1.6834x over previous
//
#include <hip/hip_runtime.h>
#include <hip/hip_bf16.h>

// LSTM: N=640 seqs (B*Q fused), T=100, D=H=512. Inputs fp32; d_out fp32.
// R12 on R11 (passing, 2273us = 22.7us/step, pipes <7% busy):
//   R11 post-mortem: uniform 1 block/CU was SLOWER than R9's ragged 320
//   -> straggler theory falsified. Real limit: serial per-step chain
//   (stage->GEMM->poll->LLC h-stage->GEMM->epilogue->publish) with ZERO
//   TLP: when wave0 spins and waves 1-3 sit at the barrier, the CU issues
//   nothing. Plus R10/R11's backoff-less 255-block poll storm on two LLC
//   lines (22.6ms outlier = flag stores starved by poll arbitration).
//   Fix: TWO independent chains per CU.
//   - 16 groups x 40 seqs x 32 hcol-blocks = 512 blocks = exactly 2/CU.
//     Group g = bids ≡ g (mod 16) -> group's 32 blocks on one XCD
//     (bid%8=g%8, empirical; perf-only), 2 groups/XCD. When chain A
//     stalls, chain B's 4 waves issue -> ~2x issue occupancy.
//   - M padded 40->48 (3 x 16-row MFMA tiles); rows 40-47 LDS garbage,
//     never stored (guard sl<40). LDS 48KB/block -> 96KB/CU;
//     __launch_bounds__(256,2) caps VGPR 256 (R11 used 200, fits) ->
//     all 512 blocks co-resident by capacity (deadlock-safe, no coop).
//   - poll backoff restored: s_sleep(1) between rounds (R9 pattern).
//   Unchanged proven protocol: h via relaxed AGENT atomics (write-through
//   LLC stores / LLC loads, NO fences -> no buffer_inv/wbl2), publish =
//   vmcnt(0) drain + barrier + own-flag store, per-producer flags, x-GEMM
//   before the wait, t=0 skips h-phase, weights in 128 VGPRs loaded once,
//   c in regs, biases preloaded, fast tanh, pair-packed h stores,
//   XOR-swizzled LDS rows, G overlays A. Same accumulation order -> same
//   numerics (absmax 0.00390625).

#define T_ 100
#define D_ 512
#define H_ 512
#define N_ 640
#define NSB 16       // seq-groups (2 per XCD)
#define MS  40       // real seqs per group
#define MP  48       // padded rows (3 x 16 MFMA tiles)
#define NGR 32       // hcol groups (16 cols x 4 gates each)
#define HALFB 24576  // bytes per half-K LDS buffer (48 rows x 512 B)

using short8  = __attribute__((ext_vector_type(8))) short;  // 8 bf16
using floatx4 = __attribute__((ext_vector_type(4))) float;  // MFMA C/D

__device__ __forceinline__ float sigmoidf_(float x) {
    return 1.0f / (1.0f + __expf(-x));
}

__device__ __forceinline__ float tanhf_(float x) {  // fast, |err|~1e-7
    const float e = __expf(2.0f * x);
    return 1.0f - 2.0f / (e + 1.0f);
}

__device__ __forceinline__ unsigned short f2bf(float f) {  // RNE, finite inputs
    union { float f; unsigned int u; } v; v.f = f;
    unsigned int u = v.u;
    u += 0x7fffu + ((u >> 16) & 1u);
    return (unsigned short)(u >> 16);
}

__device__ __forceinline__ short8 cvt8(const float* __restrict__ p) {
    const float4 a = *(const float4*)p;
    const float4 b = *(const float4*)(p + 4);
    short8 r;
    r[0] = (short)f2bf(a.x); r[1] = (short)f2bf(a.y);
    r[2] = (short)f2bf(a.z); r[3] = (short)f2bf(a.w);
    r[4] = (short)f2bf(b.x); r[5] = (short)f2bf(b.y);
    r[6] = (short)f2bf(b.z); r[7] = (short)f2bf(b.w);
    return r;
}

// fp32 -> bf16, 8 elements/thread
__global__ __launch_bounds__(256) void cvt_bf16(const float* __restrict__ src,
                                                unsigned short* __restrict__ dst, int n) {
    const int i = (blockIdx.x * 256 + threadIdx.x) * 8;
    if (i < n) {
        const float4 a = *(const float4*)(src + i);
        const float4 b = *(const float4*)(src + i + 4);
        ushort4 o0, o1;
        o0.x = f2bf(a.x); o0.y = f2bf(a.y); o0.z = f2bf(a.z); o0.w = f2bf(a.w);
        o1.x = f2bf(b.x); o1.y = f2bf(b.y); o1.z = f2bf(b.z); o1.w = f2bf(b.w);
        *(ushort4*)(dst + i)     = o0;
        *(ushort4*)(dst + i + 4) = o1;
    }
}

template <bool XBF>
__global__ __launch_bounds__(256, 2) void lstm_persist(
    const void* __restrict__ xsrc,             // [N,T,D] bf16 (XBF) else fp32
    const __hip_bfloat16* __restrict__ Wih,    // [4H, D] bf16
    const __hip_bfloat16* __restrict__ Whh,    // [4H, H] bf16
    const float* __restrict__ bih,             // [4H]
    const float* __restrict__ bhh,             // [4H]
    __hip_bfloat16* __restrict__ hbuf,         // ping/pong [2][N,H] bf16
    float* __restrict__ out,                   // d_out fp32 [N,H]
    int* __restrict__ flags)                   // [NSB][NGR] step flags (zeroed)
{
    __shared__ unsigned char SMEM[2 * HALFB];  // 48 KiB: A(2 half-K bufs) ∪ G

    const int tid = threadIdx.x;
    const int bid = blockIdx.x;
    const int sb   = bid & 15;   // group; bid%8 = XCD (empirical; perf-only)
    const int grp  = bid >> 4;   // 0..31 hcol block
    const int gate = tid >> 6;
    const int lane = tid & 63;
    const int l15  = lane & 15;
    const int quad = lane >> 4;
    const int seq0 = sb * MS;
    const int hc0  = grp * 16;

    const int r = gate * H_ + hc0 + l15;  // W row (output gate-col) for this lane

    // ---- weight slice in registers, loaded ONCE ----
    short8 wreg[2][4][4];  // [phase][k-128chunk][ki]; cols chunk*128+ki*32+quad*8
    {
        const __hip_bfloat16* w0 = Wih + (size_t)r * 512 + quad * 8;
        const __hip_bfloat16* w1 = Whh + (size_t)r * 512 + quad * 8;
        #pragma unroll
        for (int c = 0; c < 4; ++c)
            #pragma unroll
            for (int k = 0; k < 4; ++k) {
                wreg[0][c][k] = *(const short8*)(w0 + c * 128 + k * 32);
                wreg[1][c][k] = *(const short8*)(w1 + c * 128 + k * 32);
            }
    }

    // ---- fixed epilogue column: preload bias sums ----
    const int colj = hc0 + (tid & 15);
    const float bi = bih[0 * H_ + colj] + bhh[0 * H_ + colj];
    const float bf = bih[1 * H_ + colj] + bhh[1 * H_ + colj];
    const float bg = bih[2 * H_ + colj] + bhh[2 * H_ + colj];
    const float bo = bih[3 * H_ + colj] + bhh[3 * H_ + colj];

    float creg[3] = {0.f, 0.f, 0.f};  // c state, block-exclusive (rows < 40 valid)

    const float*          af0 = XBF ? nullptr : (const float*)xsrc + (size_t)seq0 * T_ * D_;
    const __hip_bfloat16* ab0 = XBF ? (const __hip_bfloat16*)xsrc + (size_t)seq0 * T_ * D_ : nullptr;
    const size_t nH = (size_t)N_ * H_;
    float* G = (float*)SMEM;  // [4][48][17] overlay, epilogue only (13056 B)

    #pragma unroll 1
    for (int t = 0; t < T_; ++t) {
        const __hip_bfloat16* hp = hbuf + ((t & 1) ? nH : 0);
        __hip_bfloat16*       hn = hbuf + ((t & 1) ? 0 : nH);

        floatx4 acc[3] = {};

        // ---- stage x_t tile: 40 real rows x 512 cols (rows 40-47 unused) ----
        {
            const size_t astr = (size_t)T_ * D_;
            const size_t toff = (size_t)t * D_;
            #pragma unroll
            for (int u = 0; u < 10; ++u) {
                const int slot = u * 256 + tid;   // 2560 x 16B slots
                const int row  = slot >> 6;       // 0..39
                const int c32  = slot & 63;       // 16B unit within row
                const int half = c32 >> 5;
                const int c16  = c32 & 31;
                short8 v;
                if (XBF) v = *(const short8*)(ab0 + row * astr + toff + c32 * 8);
                else     v = cvt8(af0 + row * astr + toff + c32 * 8);
                *(short8*)(SMEM + half * HALFB + row * 512 +
                           ((c16 * 16) ^ ((row & 7) * 16))) = v;
            }
        }
        __syncthreads();  // (1) stage done
        // ---- x GEMM: K=512, 48 MFMA (before the wait: overlaps skew) ----
        #pragma unroll
        for (int kk = 0; kk < 16; ++kk) {
            const short8 bfrag = wreg[0][kk >> 2][kk & 3];
            const int half = kk >> 3, kk8 = kk & 7;
            #pragma unroll
            for (int mi = 0; mi < 3; ++mi) {
                const int row = mi * 16 + l15;    // 0..47 (rows>=40 garbage, ok)
                const short8 afrag = *(const short8*)(
                    SMEM + half * HALFB + row * 512 +
                    (((kk8 * 64) + (quad * 16)) ^ ((row & 7) * 16)));
                acc[mi] = __builtin_amdgcn_mfma_f32_16x16x32_bf16(afrag, bfrag,
                                                                  acc[mi], 0, 0, 0);
            }
        }

        if (t > 0) {
            // ---- wait: wave0 lanes 0-31 poll group flags, s_sleep backoff ----
            if (tid < 64) {
                const int* fp = flags + sb * 32 + (tid & 31);
                int v = 0x7fffffff;
                for (;;) {
                    if (tid < 32)
                        v = __hip_atomic_load(fp, __ATOMIC_RELAXED,
                                              __HIP_MEMORY_SCOPE_AGENT);
                    if (__all(v >= t)) break;
                    __builtin_amdgcn_s_sleep(1);
                }
            }
            __syncthreads();  // (2) h ready; all x-GEMM A-reads done

            // ---- stage h tile (40 rows x 512) via LLC atomic loads ----
            const unsigned long long* hp8 =
                (const unsigned long long*)(hp + (size_t)seq0 * H_);
            #pragma unroll
            for (int u = 0; u < 20; ++u) {
                const int slot = u * 256 + tid;   // 5120 x 8B slots
                const int row  = slot >> 7;       // 0..39
                const int c64  = slot & 127;      // 8B unit within row
                const int half = c64 >> 6;
                const int c8   = c64 & 63;
                const unsigned long long v = __hip_atomic_load(
                    hp8 + row * 128 + c64, __ATOMIC_RELAXED,
                    __HIP_MEMORY_SCOPE_AGENT);
                *(unsigned long long*)(SMEM + half * HALFB + row * 512 +
                                       ((c8 * 8) ^ ((row & 7) * 16))) = v;
            }
            __syncthreads();  // (3) h staged
            // ---- h GEMM: K=512, 48 MFMA ----
            #pragma unroll
            for (int kk = 0; kk < 16; ++kk) {
                const short8 bfrag = wreg[1][kk >> 2][kk & 3];
                const int half = kk >> 3, kk8 = kk & 7;
                #pragma unroll
                for (int mi = 0; mi < 3; ++mi) {
                    const int row = mi * 16 + l15;
                    const short8 afrag = *(const short8*)(
                        SMEM + half * HALFB + row * 512 +
                        (((kk8 * 64) + (quad * 16)) ^ ((row & 7) * 16)));
                    acc[mi] = __builtin_amdgcn_mfma_f32_16x16x32_bf16(afrag, bfrag,
                                                                      acc[mi], 0, 0, 0);
                }
            }
        }

        // ---- epilogue: G overlays A (all A-reads done after barrier) ----
        __syncthreads();  // (4) A-reads complete before G overwrites
        // C/D: col = lane&15 (hcol), row = quad*4 + reg (seq)
        #pragma unroll
        for (int mi = 0; mi < 3; ++mi)
            #pragma unroll
            for (int rg = 0; rg < 4; ++rg)
                G[(gate * MP + mi * 16 + quad * 4 + rg) * 17 + l15] = acc[mi][rg];
        __syncthreads();  // (5) G visible

        #pragma unroll
        for (int i = 0; i < 3; ++i) {
            const int sl = (tid >> 4) + 16 * i;   // 0..47
            const int cc = tid & 15;
            const int n  = seq0 + sl;

            const float gi = sigmoidf_(G[(0 * MP + sl) * 17 + cc] + bi);
            const float gf = sigmoidf_(G[(1 * MP + sl) * 17 + cc] + bf);
            const float gg = tanhf_(G[(2 * MP + sl) * 17 + cc] + bg);
            const float go = sigmoidf_(G[(3 * MP + sl) * 17 + cc] + bo);

            const float cn = gf * creg[i] + gi * gg;
            creg[i] = cn;
            const float hv = go * tanhf_(cn);

            if (sl < MS) {  // rows 40-47 are padding: never stored
                if (t < T_ - 1) {
                    // lanes (tid,tid^1) hold cols (cc,cc^1): pack -> one 32-bit
                    // LLC write-through store (no fence needed)
                    const unsigned int hb    = f2bf(hv);
                    const unsigned int other = __shfl_xor((int)hb, 1, 64);
                    if ((tid & 1) == 0) {
                        unsigned int packed = hb | (other << 16);
                        __hip_atomic_store(
                            (unsigned int*)((unsigned short*)hn + (size_t)n * H_ + colj),
                            packed, __ATOMIC_RELAXED, __HIP_MEMORY_SCOPE_AGENT);
                    }
                } else {
                    out[(size_t)n * H_ + colj] = hv;  // kernel-end release covers d_out
                }
            }
        }

        // ---- publish h(t): drain stores, block barrier, own-flag store ----
        if (t < T_ - 1) {
            asm volatile("s_waitcnt vmcnt(0)" ::: "memory");  // h stores at LLC
            __syncthreads();  // (6) whole block drained; also guards SMEM reuse
            if (tid == 0)
                __hip_atomic_store(flags + sb * 32 + grp, t + 1,
                                   __ATOMIC_RELAXED, __HIP_MEMORY_SCOPE_AGENT);
        }
    }
}

extern "C" void kernel_launch(void* const* d_in, const int* in_sizes, int n_in,
                              void* d_out, int out_size, void* d_ws, size_t ws_size,
                              hipStream_t stream) {
    const float* x    = (const float*)d_in[0];
    const float* Wihf = (const float*)d_in[1];
    const float* Whhf = (const float*)d_in[2];
    const float* bih  = (const float*)d_in[3];
    const float* bhh  = (const float*)d_in[4];

    const size_t nW = (size_t)4 * H_ * D_;   // 1,048,576
    const size_t nX = (size_t)N_ * T_ * D_;  // 32,768,000
    const size_t nH = (size_t)N_ * H_;       // 327,680

    // ws: Wb | Ub | flags | h ping+pong | [xb]
    char* p = (char*)d_ws;
    __hip_bfloat16* Wb = (__hip_bfloat16*)p;  p += nW * 2;
    __hip_bfloat16* Ub = (__hip_bfloat16*)p;  p += nW * 2;
    int* flags = (int*)p;                     p += 4096;   // 2048 B used
    __hip_bfloat16* h2 = (__hip_bfloat16*)p;  p += nH * 2 * 2;
    const size_t need_xb = (size_t)(p - (char*)d_ws) + nX * 2;
    const bool use_xb = ws_size >= need_xb;
    __hip_bfloat16* xb = use_xb ? (__hip_bfloat16*)p : nullptr;

    cvt_bf16<<<(int)(nW / (256 * 8)), 256, 0, stream>>>(Wihf, (unsigned short*)Wb, (int)nW);
    cvt_bf16<<<(int)(nW / (256 * 8)), 256, 0, stream>>>(Whhf, (unsigned short*)Ub, (int)nW);
    if (use_xb)
        cvt_bf16<<<(int)(nX / (256 * 8)), 256, 0, stream>>>(x, (unsigned short*)xb, (int)nX);

    hipMemsetAsync(flags, 0, 4096, stream);

    const int nblk = NSB * NGR;  // 512 blocks = exactly 2/CU; all co-resident
    if (use_xb)
        lstm_persist<true><<<nblk, 256, 0, stream>>>(xb, Wb, Ub, bih, bhh, h2,
                                                     (float*)d_out, flags);
    else
        lstm_persist<false><<<nblk, 256, 0, stream>>>(x, Wb, Ub, bih, bhh, h2,
                                                      (float*)d_out, flags);
}